// Round 1
// baseline (973.188 us; speedup 1.0000x reference)
//
#include <hip/hip_runtime.h>
#include <math.h>

#define BB   16
#define SS   4096
#define DD   64
#define HH   8
#define NBH  32      // half-buckets (rotations last dim)
#define NB   64      // local buckets per hash
#define NCH  512     // total chunks per batch = HH * (SS/64 / 64)... = 8*64

// ---------------------------------------------------------------------------
// Kernel 1: LSH hashing.  rot[b,h,t,i] = sum_f qk[b,t,f]*rotations[b,f,h,i],
// bucket = argmax over [rot, -rot] (first-max wins, matching np.argmax).
// fp64 accumulation so the argmax matches an exact/np reference.
// ---------------------------------------------------------------------------
__global__ __launch_bounds__(256) void k_hash(
    const float* __restrict__ qk, const float* __restrict__ rot,
    int* __restrict__ bucket_local, float* __restrict__ buckets_out) {
  const int bh = blockIdx.x;
  const int b = bh >> 3, h = bh & 7;
  const int t = blockIdx.y * 256 + threadIdx.x;

  const float4* q4 = (const float4*)(qk + ((size_t)(b * SS + t)) * DD);
  // rotations[b,f,h,i] at ((b*DD+f)*HH+h)*NBH + i
  const float* rp = rot + (size_t)b * (DD * HH * NBH) + h * NBH;

  double acc[NBH];
#pragma unroll
  for (int i = 0; i < NBH; i++) acc[i] = 0.0;

  for (int f4 = 0; f4 < 16; f4++) {
    float4 qv = q4[f4];
    float qa[4] = {qv.x, qv.y, qv.z, qv.w};
#pragma unroll
    for (int ff = 0; ff < 4; ff++) {
      double qd = (double)qa[ff];
      const float4* r4 = (const float4*)(rp + (size_t)(f4 * 4 + ff) * (HH * NBH));
#pragma unroll
      for (int i4 = 0; i4 < 8; i4++) {
        float4 rv = r4[i4];
        acc[i4 * 4 + 0] += qd * (double)rv.x;
        acc[i4 * 4 + 1] += qd * (double)rv.y;
        acc[i4 * 4 + 2] += qd * (double)rv.z;
        acc[i4 * 4 + 3] += qd * (double)rv.w;
      }
    }
  }

  double best = -1.0e300;
  int bi = 0;
#pragma unroll
  for (int i = 0; i < 64; i++) {
    double vv = (i < NBH) ? acc[i] : -acc[i - NBH];
    if (vv > best) { best = vv; bi = i; }   // strict > : first max wins
  }
  bucket_local[(size_t)bh * SS + t] = bi;
  buckets_out[(size_t)b * (HH * SS) + (size_t)h * SS + t] = (float)(h * NB + bi);
}

// ---------------------------------------------------------------------------
// Kernel 2: stable counting sort per (b,h): sort t=0..4095 by local bucket.
// sort_t[b,h,p] = original position t of sorted slot p.
// ---------------------------------------------------------------------------
__global__ __launch_bounds__(256) void k_sort(
    const int* __restrict__ bucket_local, int* __restrict__ sort_t) {
  __shared__ int lb[SS];
  __shared__ int cnt[NB];
  __shared__ int off[NB];
  const int bh = blockIdx.x;
  const int tid = threadIdx.x;
  const int* src = bucket_local + (size_t)bh * SS;
  for (int k = tid; k < SS; k += 256) lb[k] = src[k];
  if (tid < NB) cnt[tid] = 0;
  __syncthreads();
  for (int k = tid; k < SS; k += 256) atomicAdd(&cnt[lb[k]], 1);
  __syncthreads();
  if (tid == 0) {
    int r = 0;
    for (int i = 0; i < NB; i++) { off[i] = r; r += cnt[i]; }
  }
  __syncthreads();
  if (tid < NB) {
    const int my = tid;
    int pos = off[my];
    int* dst = sort_t + (size_t)bh * SS;
    for (int t = 0; t < SS; t++) {
      if (lb[t] == my) { dst[pos++] = t; }
    }
  }
}

// ---------------------------------------------------------------------------
// Kernel 3: chunked attention. One block per (b, global chunk c in [0,512)).
// 64 queries x 128 keys (own chunk + previous chunk with global wrap).
// Accumulates num += o*exp(lse), den += exp(lse) via fp32 global atomics.
// ---------------------------------------------------------------------------
__global__ __launch_bounds__(256) void k_attn(
    const float* __restrict__ qk, const float* __restrict__ v,
    const int* __restrict__ sort_t, float* __restrict__ num,
    float* __restrict__ den) {
  const int blk = blockIdx.x;
  const int b = blk >> 9;
  const int c = blk & 511;
  const int h = c >> 6, cc = c & 63;
  const int cp = (c + 511) & 511;       // previous chunk, global wrap
  const int hp = cp >> 6, ccp = cp & 63;

  __shared__ union {
    struct {                      // phase A (48K + small)
      float qt[DD * 64];          // [f][qi]
      float kt[DD * 128];         // [f][j]  (raw, un-normalized)
      int   tq[64];
      int   tk[128];
      float nrm[128];             // sumsq -> 0.125/(norm+eps)
      float red[16 * 64];         // [key-group][qi]
      float rmax[64];
      float rsum[64];
    } a;
    struct {                      // phase B (exactly 64K)
      float pt[128 * 64];         // [j][qi]
      float vs[128 * 64];         // [j][f]
    } p;
  } sm;

  const int tid = threadIdx.x;

  // ---- phase 0: indices ----
  if (tid < 64)
    sm.a.tq[tid] = sort_t[((size_t)b * HH + h) * SS + cc * 64 + tid];
  if (tid >= 128) {
    const int j = tid - 128;
    const size_t src = (j < 64) ? (((size_t)b * HH + h) * SS + cc * 64 + j)
                                : (((size_t)b * HH + hp) * SS + ccp * 64 + (j - 64));
    sm.a.tk[j] = sort_t[src];
  }
  if (tid >= 64 && tid < 192) sm.a.nrm[tid - 64] = 0.f;
  __syncthreads();

  // ---- phase 1: stage q (transposed), k (transposed) + sumsq ----
  {
    const int qi = tid >> 2, qq = tid & 3;
    const float4* qsrc =
        (const float4*)(qk + ((size_t)b * SS + sm.a.tq[qi]) * DD) + qq * 4;
#pragma unroll
    for (int k4 = 0; k4 < 4; k4++) {
      float4 val = qsrc[k4];
      const int f = qq * 16 + k4 * 4;
      sm.a.qt[(f + 0) * 64 + qi] = val.x;
      sm.a.qt[(f + 1) * 64 + qi] = val.y;
      sm.a.qt[(f + 2) * 64 + qi] = val.z;
      sm.a.qt[(f + 3) * 64 + qi] = val.w;
    }
    const int j = tid >> 1, hhf = tid & 1;
    const float4* ksrc =
        (const float4*)(qk + ((size_t)b * SS + sm.a.tk[j]) * DD) + hhf * 8;
    float ss = 0.f;
#pragma unroll
    for (int k4 = 0; k4 < 8; k4++) {
      float4 val = ksrc[k4];
      const int f = hhf * 32 + k4 * 4;
      sm.a.kt[(f + 0) * 128 + j] = val.x;
      sm.a.kt[(f + 1) * 128 + j] = val.y;
      sm.a.kt[(f + 2) * 128 + j] = val.z;
      sm.a.kt[(f + 3) * 128 + j] = val.w;
      ss += val.x * val.x + val.y * val.y + val.z * val.z + val.w * val.w;
    }
    atomicAdd(&sm.a.nrm[j], ss);
  }
  __syncthreads();
  if (tid < 128) {
    const float n = sqrtf(sm.a.nrm[tid]) + 1e-6f;
    sm.a.nrm[tid] = 0.125f / n;   // fold in d^-0.5
  }
  // v gather into registers (LDS write deferred until phase B is safe)
  float4 vreg[8];
  {
    const int j = tid >> 1, hhf = tid & 1;
    const float4* vsrc =
        (const float4*)(v + ((size_t)b * SS + sm.a.tk[j]) * DD) + hhf * 8;
#pragma unroll
    for (int k4 = 0; k4 < 8; k4++) vreg[k4] = vsrc[k4];
  }
  __syncthreads();   // nrm->scale visible to everyone

  // ---- phase 2: QK^T, 4x8 register tile per thread ----
  const int qi0 = (tid & 15) * 4;
  const int j0g = (tid >> 4) * 8;
  const int kg = tid >> 4;
  float acc[4][8];
#pragma unroll
  for (int i = 0; i < 4; i++)
#pragma unroll
    for (int j = 0; j < 8; j++) acc[i][j] = 0.f;

#pragma unroll 8
  for (int f = 0; f < DD; f++) {
    float4 qv = *(const float4*)&sm.a.qt[f * 64 + qi0];
    float4 k0 = *(const float4*)&sm.a.kt[f * 128 + j0g];
    float4 k1 = *(const float4*)&sm.a.kt[f * 128 + j0g + 4];
    float qa[4] = {qv.x, qv.y, qv.z, qv.w};
    float ka[8] = {k0.x, k0.y, k0.z, k0.w, k1.x, k1.y, k1.z, k1.w};
#pragma unroll
    for (int i = 0; i < 4; i++)
#pragma unroll
      for (int j = 0; j < 8; j++) acc[i][j] = fmaf(qa[i], ka[j], acc[i][j]);
  }

  // ---- scale + self-mask ----
  int tqr[4];
#pragma unroll
  for (int i = 0; i < 4; i++) tqr[i] = sm.a.tq[qi0 + i];
  int tkr[8]; float scl[8];
#pragma unroll
  for (int j = 0; j < 8; j++) {
    tkr[j] = sm.a.tk[j0g + j];
    scl[j] = sm.a.nrm[j0g + j];
  }
#pragma unroll
  for (int i = 0; i < 4; i++)
#pragma unroll
    for (int j = 0; j < 8; j++) {
      const float dv = acc[i][j] * scl[j];
      acc[i][j] = (tqr[i] == tkr[j]) ? -50000.0f : dv;
    }

  // ---- softmax (row stats across the 16 key-groups via LDS) ----
  float pmax[4];
#pragma unroll
  for (int i = 0; i < 4; i++) {
    float m = acc[i][0];
#pragma unroll
    for (int j = 1; j < 8; j++) m = fmaxf(m, acc[i][j]);
    pmax[i] = m;
  }
#pragma unroll
  for (int i = 0; i < 4; i++) sm.a.red[kg * 64 + qi0 + i] = pmax[i];
  __syncthreads();
  if (tid < 64) {
    float m = -3.0e38f;
#pragma unroll
    for (int g = 0; g < 16; g++) m = fmaxf(m, sm.a.red[g * 64 + tid]);
    sm.a.rmax[tid] = m;
  }
  __syncthreads();
  float psum[4];
#pragma unroll
  for (int i = 0; i < 4; i++) {
    const float rm = sm.a.rmax[qi0 + i];
    float s = 0.f;
#pragma unroll
    for (int j = 0; j < 8; j++) {
      const float e = __expf(acc[i][j] - rm);
      acc[i][j] = e;
      s += e;
    }
    psum[i] = s;
  }
#pragma unroll
  for (int i = 0; i < 4; i++) sm.a.red[kg * 64 + qi0 + i] = psum[i];
  __syncthreads();
  if (tid < 64) {
    float s = 0.f;
#pragma unroll
    for (int g = 0; g < 16; g++) s += sm.a.red[g * 64 + tid];
    sm.a.rsum[tid] = s;
  }
  __syncthreads();
  float lse[4], isum[4];
#pragma unroll
  for (int i = 0; i < 4; i++) {
    const float rm = sm.a.rmax[qi0 + i];
    const float s = sm.a.rsum[qi0 + i];
    isum[i] = 1.0f / s;
    lse[i] = __logf(s) + rm;
  }
  __syncthreads();   // everyone done with region-a -> safe to clobber

  // ---- stage probs (transposed) and v into phase-B LDS ----
#pragma unroll
  for (int j = 0; j < 8; j++)
#pragma unroll
    for (int i = 0; i < 4; i++)
      sm.p.pt[(j0g + j) * 64 + qi0 + i] = acc[i][j] * isum[i];
  {
    const int j = tid >> 1, hhf = tid & 1;
#pragma unroll
    for (int k4 = 0; k4 < 8; k4++)
      *(float4*)&sm.p.vs[j * 64 + hhf * 32 + k4 * 4] = vreg[k4];
  }
  __syncthreads();

  // ---- phase 3: P @ V, 4x4 register tile per thread ----
  const int f0 = (tid >> 4) * 4;
  float o[4][4];
#pragma unroll
  for (int i = 0; i < 4; i++)
#pragma unroll
    for (int j = 0; j < 4; j++) o[i][j] = 0.f;

#pragma unroll 8
  for (int j = 0; j < 128; j++) {
    float4 pv = *(const float4*)&sm.p.pt[j * 64 + qi0];
    float4 vv = *(const float4*)&sm.p.vs[j * 64 + f0];
    float pa[4] = {pv.x, pv.y, pv.z, pv.w};
    float va[4] = {vv.x, vv.y, vv.z, vv.w};
#pragma unroll
    for (int i = 0; i < 4; i++)
#pragma unroll
      for (int j2 = 0; j2 < 4; j2++) o[i][j2] = fmaf(pa[i], va[j2], o[i][j2]);
  }

  // ---- epilogue: num += o*exp(lse), den += exp(lse) ----
#pragma unroll
  for (int i = 0; i < 4; i++) {
    const float w = __expf(lse[i]);
    float* dst = num + ((size_t)b * SS + tqr[i]) * DD + f0;
#pragma unroll
    for (int j = 0; j < 4; j++) atomicAdd(dst + j, o[i][j] * w);
    if (kg == 0) atomicAdd(den + (size_t)b * SS + tqr[i], w);
  }
}

// ---------------------------------------------------------------------------
// Kernel 4: out = num / den (in place on d_out's first B*S*D floats)
// ---------------------------------------------------------------------------
__global__ __launch_bounds__(256) void k_final(float* __restrict__ o,
                                               const float* __restrict__ den) {
  const size_t i = (size_t)blockIdx.x * 256 + threadIdx.x;
  o[i] = o[i] / den[i >> 6];
}

extern "C" void kernel_launch(void* const* d_in, const int* in_sizes, int n_in,
                              void* d_out, int out_size, void* d_ws,
                              size_t ws_size, hipStream_t stream) {
  const float* qk  = (const float*)d_in[0];
  const float* v   = (const float*)d_in[1];
  const float* rot = (const float*)d_in[2];
  // d_in[3] = seed_ (unused by the math)

  float* out_num = (float*)d_out;                       // B*S*D floats
  float* buckets_out = out_num + (size_t)BB * SS * DD;  // B*H*S floats

  int* bucket_local = (int*)d_ws;                           // B*H*S ints
  int* sort_t = bucket_local + (size_t)BB * HH * SS;        // B*H*S ints
  float* den = (float*)(sort_t + (size_t)BB * HH * SS);     // B*S floats

  hipMemsetAsync(out_num, 0, (size_t)BB * SS * DD * sizeof(float), stream);
  hipMemsetAsync(den, 0, (size_t)BB * SS * sizeof(float), stream);

  k_hash<<<dim3(BB * HH, SS / 256), 256, 0, stream>>>(qk, rot, bucket_local,
                                                      buckets_out);
  k_sort<<<BB * HH, 256, 0, stream>>>(bucket_local, sort_t);
  k_attn<<<BB * NCH, 256, 0, stream>>>(qk, v, sort_t, out_num, den);
  k_final<<<(BB * SS * DD) / 256, 256, 0, stream>>>(out_num, den);
}

// Round 2
// 318.786 us; speedup vs baseline: 3.0528x; 3.0528x over previous
//
#include <hip/hip_runtime.h>
#include <math.h>

#define BB   16
#define SS   4096
#define DD   64
#define HH   8
#define NBH  32
#define NB   64
#define NCH  512     // global chunks per batch = HH * 64

typedef __attribute__((ext_vector_type(8))) short s16x8;   // 8 bf16
typedef __attribute__((ext_vector_type(4))) float f32x4;

static __device__ __forceinline__ unsigned short f2bf(float x) {
  union { float f; unsigned u; } a; a.f = x;
  unsigned r = a.u + 0x7fffu + ((a.u >> 16) & 1u);   // RNE
  return (unsigned short)(r >> 16);
}

// ---------------------------------------------------------------------------
// Kernel 1: LSH hashing — VERBATIM from R1 (fp64 accumulation; bucket argmax
// must stay byte-identical: flips change output-1 by O(100)).
// ---------------------------------------------------------------------------
__global__ __launch_bounds__(256) void k_hash(
    const float* __restrict__ qk, const float* __restrict__ rot,
    int* __restrict__ bucket_local, float* __restrict__ buckets_out) {
  const int bh = blockIdx.x;
  const int b = bh >> 3, h = bh & 7;
  const int t = blockIdx.y * 256 + threadIdx.x;

  const float4* q4 = (const float4*)(qk + ((size_t)(b * SS + t)) * DD);
  const float* rp = rot + (size_t)b * (DD * HH * NBH) + h * NBH;

  double acc[NBH];
#pragma unroll
  for (int i = 0; i < NBH; i++) acc[i] = 0.0;

  for (int f4 = 0; f4 < 16; f4++) {
    float4 qv = q4[f4];
    float qa[4] = {qv.x, qv.y, qv.z, qv.w};
#pragma unroll
    for (int ff = 0; ff < 4; ff++) {
      double qd = (double)qa[ff];
      const float4* r4 = (const float4*)(rp + (size_t)(f4 * 4 + ff) * (HH * NBH));
#pragma unroll
      for (int i4 = 0; i4 < 8; i4++) {
        float4 rv = r4[i4];
        acc[i4 * 4 + 0] += qd * (double)rv.x;
        acc[i4 * 4 + 1] += qd * (double)rv.y;
        acc[i4 * 4 + 2] += qd * (double)rv.z;
        acc[i4 * 4 + 3] += qd * (double)rv.w;
      }
    }
  }

  double best = -1.0e300;
  int bi = 0;
#pragma unroll
  for (int i = 0; i < 64; i++) {
    double vv = (i < NBH) ? acc[i] : -acc[i - NBH];
    if (vv > best) { best = vv; bi = i; }
  }
  bucket_local[(size_t)bh * SS + t] = bi;
  buckets_out[(size_t)b * (HH * SS) + (size_t)h * SS + t] = (float)(h * NB + bi);
}

// ---------------------------------------------------------------------------
// Kernel 2: parallel stable counting-rank sort per (b,h). 256 thr x 16 elems.
// Produces the identical permutation to a stable sort by (bucket, t), plus
// the inverse permutation ipos.
// ---------------------------------------------------------------------------
__global__ __launch_bounds__(256) void k_sort(
    const int* __restrict__ bucket_local, int* __restrict__ sort_t,
    int* __restrict__ ipos) {
  __shared__ unsigned short lb[SS];              // 8 KB
  __shared__ unsigned char  cnt[NB][256];        // 16 KB
  __shared__ unsigned short pfx[NB][256];        // 32 KB
  __shared__ int part[NB][4];
  __shared__ int tot[NB];
  __shared__ int base[NB];

  const int bh = blockIdx.x;
  const int tid = threadIdx.x;
  const int* src = bucket_local + (size_t)bh * SS;

  // zero counts
  int* czero = (int*)&cnt[0][0];
#pragma unroll
  for (int i = 0; i < 16; i++) czero[tid + i * 256] = 0;
  __syncthreads();

  // count (column tid owned by this thread only)
#pragma unroll
  for (int i = 0; i < 16; i++) {
    const int t = tid * 16 + i;
    const int v = src[t];
    lb[t] = (unsigned short)v;
    cnt[v][tid]++;
  }
  __syncthreads();

  // segment partials: thread (bk, sg) sums 64 columns
  {
    const int bk = tid & 63, sg = tid >> 6;
    int s = 0;
#pragma unroll 8
    for (int i = 0; i < 64; i++) s += cnt[bk][sg * 64 + i];
    part[bk][sg] = s;
  }
  __syncthreads();
  if (tid < NB) tot[tid] = part[tid][0] + part[tid][1] + part[tid][2] + part[tid][3];
  __syncthreads();
  if (tid == 0) {
    int r = 0;
    for (int i = 0; i < NB; i++) { base[i] = r; r += tot[i]; }
  }
  __syncthreads();
  // per-(bucket,thread) exclusive prefix
  {
    const int bk = tid & 63, sg = tid >> 6;
    int run = base[bk];
    for (int s = 0; s < sg; s++) run += part[bk][s];
#pragma unroll 8
    for (int i = 0; i < 64; i++) {
      const int th = sg * 64 + i;
      pfx[bk][th] = (unsigned short)run;
      run += cnt[bk][th];
    }
  }
  __syncthreads();
  // scatter (pfx[bk][tid] owned by thread tid now)
  int* st = sort_t + (size_t)bh * SS;
  int* ip = ipos + (size_t)bh * SS;
#pragma unroll
  for (int i = 0; i < 16; i++) {
    const int t = tid * 16 + i;
    const int bk = lb[t];
    const int pos = pfx[bk][tid]++;
    st[pos] = t;
    ip[t] = pos;
  }
}

// ---------------------------------------------------------------------------
// Kernel 3 (big-ws path): chunked attention with bf16 MFMA.
// One block = (b, global chunk c). Writes so (sorted order, fp32) + lse.
// ---------------------------------------------------------------------------
__global__ __launch_bounds__(256) void k_attn_mfma(
    const float* __restrict__ qk, const float* __restrict__ v,
    const int* __restrict__ sort_t, float* __restrict__ so,
    float* __restrict__ lse_out) {
  const int blk = blockIdx.x;
  const int b = blk >> 9;
  const int c = blk & 511;
  const int h = c >> 6, cc = c & 63;
  const int cp = (c + 511) & 511;
  const int hp = cp >> 6, ccp = cp & 63;

  __shared__ struct __align__(16) {
    unsigned short kb[128][72];                       // normalized+scaled K, bf16
    unsigned short vt[64][136];                       // vt[f][j] = v[j][f], bf16
    union {
      unsigned short q[64][72];                       // raw Q, bf16
      unsigned short p[64][136];                      // probs, bf16
    } qp;
    int tk[128];
  } sm;

  const int tid = threadIdx.x;
  const int w = tid >> 6;          // wave id (m-tile)
  const int lane = tid & 63;
  const int quad = lane >> 4;
  const int l16 = lane & 15;

  // ---- indices (tk[0:64] is also tq) ----
  if (tid < 128) {
    const size_t srci = (tid < 64)
        ? (((size_t)b * HH + h) * SS + cc * 64 + tid)
        : (((size_t)b * HH + hp) * SS + ccp * 64 + (tid - 64));
    sm.tk[tid] = sort_t[srci];
  }
  __syncthreads();

  // ---- stage: thread (j = tid>>1, hf = tid&1) handles half a row ----
  {
    const int j = tid >> 1, hf = tid & 1;
    const int trow = sm.tk[j];
    const float4* ksrc = (const float4*)(qk + ((size_t)b * SS + trow) * DD) + hf * 8;
    float4 kv[8];
    float ss = 0.f;
#pragma unroll
    for (int k4 = 0; k4 < 8; k4++) {
      kv[k4] = ksrc[k4];
      ss += kv[k4].x * kv[k4].x + kv[k4].y * kv[k4].y +
            kv[k4].z * kv[k4].z + kv[k4].w * kv[k4].w;
    }
    const float tot = ss + __shfl_xor(ss, 1);
    const float scl = 0.125f / (sqrtf(tot) + 1e-6f);   // fold d^-0.5 + unit-length

    unsigned short tmp[32], tmq[32];
#pragma unroll
    for (int k4 = 0; k4 < 8; k4++) {
      const float va[4] = {kv[k4].x, kv[k4].y, kv[k4].z, kv[k4].w};
#pragma unroll
      for (int e = 0; e < 4; e++) {
        tmp[k4 * 4 + e] = f2bf(va[e] * scl);
        tmq[k4 * 4 + e] = f2bf(va[e]);
      }
    }
#pragma unroll
    for (int g = 0; g < 4; g++)
      *(s16x8*)&sm.kb[j][hf * 32 + g * 8] = *(const s16x8*)&tmp[g * 8];
    if (j < 64) {
#pragma unroll
      for (int g = 0; g < 4; g++)
        *(s16x8*)&sm.qp.q[j][hf * 32 + g * 8] = *(const s16x8*)&tmq[g * 8];
    }
    // V: load half row, write transposed bf16
    const float4* vsrc = (const float4*)(v + ((size_t)b * SS + trow) * DD) + hf * 8;
#pragma unroll
    for (int k4 = 0; k4 < 8; k4++) {
      float4 vv = vsrc[k4];
      const int f = hf * 32 + k4 * 4;
      sm.vt[f + 0][j] = f2bf(vv.x);
      sm.vt[f + 1][j] = f2bf(vv.y);
      sm.vt[f + 2][j] = f2bf(vv.z);
      sm.vt[f + 3][j] = f2bf(vv.w);
    }
  }
  __syncthreads();

  // ---- QK^T: wave w owns rows [w*16, w*16+16), all 8 n-tiles ----
  f32x4 acc[8];
#pragma unroll
  for (int nt = 0; nt < 8; nt++) acc[nt] = (f32x4){0.f, 0.f, 0.f, 0.f};
  {
    const s16x8 a0 = *(const s16x8*)&sm.qp.q[w * 16 + l16][quad * 8];
    const s16x8 a1 = *(const s16x8*)&sm.qp.q[w * 16 + l16][32 + quad * 8];
#pragma unroll
    for (int nt = 0; nt < 8; nt++) {
      const s16x8 b0 = *(const s16x8*)&sm.kb[nt * 16 + l16][quad * 8];
      const s16x8 b1 = *(const s16x8*)&sm.kb[nt * 16 + l16][32 + quad * 8];
      acc[nt] = __builtin_amdgcn_mfma_f32_16x16x32_bf16(a0, b0, acc[nt], 0, 0, 0);
      acc[nt] = __builtin_amdgcn_mfma_f32_16x16x32_bf16(a1, b1, acc[nt], 0, 0, 0);
    }
  }

  // ---- mask + softmax (rows live in this wave: row = w*16 + quad*4 + r) ----
  int tqr[4];
#pragma unroll
  for (int r = 0; r < 4; r++) tqr[r] = sm.tk[w * 16 + quad * 4 + r];
  int tkc[8];
#pragma unroll
  for (int nt = 0; nt < 8; nt++) tkc[nt] = sm.tk[nt * 16 + l16];

#pragma unroll
  for (int nt = 0; nt < 8; nt++)
#pragma unroll
    for (int r = 0; r < 4; r++)
      if (tqr[r] == tkc[nt]) acc[nt][r] = -50000.0f;

  float rmax[4], rsum[4], lse[4], inv[4];
#pragma unroll
  for (int r = 0; r < 4; r++) {
    float m = acc[0][r];
#pragma unroll
    for (int nt = 1; nt < 8; nt++) m = fmaxf(m, acc[nt][r]);
    m = fmaxf(m, __shfl_xor(m, 1));
    m = fmaxf(m, __shfl_xor(m, 2));
    m = fmaxf(m, __shfl_xor(m, 4));
    m = fmaxf(m, __shfl_xor(m, 8));
    rmax[r] = m;
  }
#pragma unroll
  for (int r = 0; r < 4; r++) {
    float s = 0.f;
#pragma unroll
    for (int nt = 0; nt < 8; nt++) {
      const float e = __expf(acc[nt][r] - rmax[r]);
      acc[nt][r] = e;
      s += e;
    }
    s += __shfl_xor(s, 1);
    s += __shfl_xor(s, 2);
    s += __shfl_xor(s, 4);
    s += __shfl_xor(s, 8);
    rsum[r] = s;
    inv[r] = 1.0f / s;
    lse[r] = __logf(s) + rmax[r];
  }

  // lse store (one lane per row)
  if (l16 == 0) {
#pragma unroll
    for (int r = 0; r < 4; r++) {
      const int row = w * 16 + quad * 4 + r;
      lse_out[((size_t)b * HH + h) * SS + cc * 64 + row] = lse[r];
    }
  }

  __syncthreads();   // all QK^T reads of q done -> safe to overwrite with p

  // ---- write probs bf16 (transpose C-layout -> A-layout via LDS) ----
#pragma unroll
  for (int nt = 0; nt < 8; nt++)
#pragma unroll
    for (int r = 0; r < 4; r++)
      sm.qp.p[w * 16 + quad * 4 + r][nt * 16 + l16] = f2bf(acc[nt][r] * inv[r]);
  __syncthreads();

  // ---- PV: wave w owns rows [w*16, +16), 4 f-tiles, K=128 ----
  f32x4 o[4];
#pragma unroll
  for (int ft = 0; ft < 4; ft++) o[ft] = (f32x4){0.f, 0.f, 0.f, 0.f};
#pragma unroll
  for (int kc = 0; kc < 4; kc++) {
    const s16x8 pa = *(const s16x8*)&sm.qp.p[w * 16 + l16][kc * 32 + quad * 8];
#pragma unroll
    for (int ft = 0; ft < 4; ft++) {
      const s16x8 vb = *(const s16x8*)&sm.vt[ft * 16 + l16][kc * 32 + quad * 8];
      o[ft] = __builtin_amdgcn_mfma_f32_16x16x32_bf16(pa, vb, o[ft], 0, 0, 0);
    }
  }

  // ---- store so in sorted order (coalesced 64B segments) ----
#pragma unroll
  for (int r = 0; r < 4; r++) {
    const int row = w * 16 + quad * 4 + r;
    float* dst = so + ((((size_t)b * HH + h) * SS + cc * 64 + row) << 6);
#pragma unroll
    for (int ft = 0; ft < 4; ft++) dst[ft * 16 + l16] = o[ft][r];
  }
}

// ---------------------------------------------------------------------------
// Kernel 4 (big-ws path): combine hash rounds. thread = (b,t,f).
// ---------------------------------------------------------------------------
__global__ __launch_bounds__(256) void k_combine(
    const float* __restrict__ so, const float* __restrict__ lse,
    const int* __restrict__ ipos, float* __restrict__ out) {
  const size_t idx = (size_t)blockIdx.x * 256 + threadIdx.x;
  const int f = (int)(idx & 63);
  const int t = (int)((idx >> 6) & (SS - 1));
  const int b = (int)(idx >> 18);

  int pos[HH];
  float l[HH];
#pragma unroll
  for (int h = 0; h < HH; h++) {
    pos[h] = ipos[((size_t)b * HH + h) * SS + t];
    l[h] = lse[((size_t)b * HH + h) * SS + pos[h]];
  }
  float m = l[0];
#pragma unroll
  for (int h = 1; h < HH; h++) m = fmaxf(m, l[h]);
  float den = 0.f, num = 0.f;
#pragma unroll
  for (int h = 0; h < HH; h++) {
    const float wgt = __expf(l[h] - m);
    den += wgt;
    num += wgt * so[((((size_t)b * HH + h) * SS + pos[h]) << 6) + f];
  }
  out[idx] = num / den;
}

// ---------------------------------------------------------------------------
// Fallback path (small ws): R1's atomic k_attn + divide. Proven correct.
// ---------------------------------------------------------------------------
__global__ __launch_bounds__(256) void k_attn_atomic(
    const float* __restrict__ qk, const float* __restrict__ v,
    const int* __restrict__ sort_t, float* __restrict__ num,
    float* __restrict__ den) {
  const int blk = blockIdx.x;
  const int b = blk >> 9;
  const int c = blk & 511;
  const int h = c >> 6, cc = c & 63;
  const int cp = (c + 511) & 511;
  const int hp = cp >> 6, ccp = cp & 63;

  __shared__ union {
    struct {
      float qt[DD * 64];
      float kt[DD * 128];
      int   tq[64];
      int   tk[128];
      float nrm[128];
      float red[16 * 64];
      float rmax[64];
      float rsum[64];
    } a;
    struct {
      float pt[128 * 64];
      float vs[128 * 64];
    } p;
  } sm;

  const int tid = threadIdx.x;

  if (tid < 64)
    sm.a.tq[tid] = sort_t[((size_t)b * HH + h) * SS + cc * 64 + tid];
  if (tid >= 128) {
    const int j = tid - 128;
    const size_t src = (j < 64) ? (((size_t)b * HH + h) * SS + cc * 64 + j)
                                : (((size_t)b * HH + hp) * SS + ccp * 64 + (j - 64));
    sm.a.tk[j] = sort_t[src];
  }
  if (tid >= 64 && tid < 192) sm.a.nrm[tid - 64] = 0.f;
  __syncthreads();

  {
    const int qi = tid >> 2, qq = tid & 3;
    const float4* qsrc =
        (const float4*)(qk + ((size_t)b * SS + sm.a.tq[qi]) * DD) + qq * 4;
#pragma unroll
    for (int k4 = 0; k4 < 4; k4++) {
      float4 val = qsrc[k4];
      const int f = qq * 16 + k4 * 4;
      sm.a.qt[(f + 0) * 64 + qi] = val.x;
      sm.a.qt[(f + 1) * 64 + qi] = val.y;
      sm.a.qt[(f + 2) * 64 + qi] = val.z;
      sm.a.qt[(f + 3) * 64 + qi] = val.w;
    }
    const int j = tid >> 1, hhf = tid & 1;
    const float4* ksrc =
        (const float4*)(qk + ((size_t)b * SS + sm.a.tk[j]) * DD) + hhf * 8;
    float ss = 0.f;
#pragma unroll
    for (int k4 = 0; k4 < 8; k4++) {
      float4 val = ksrc[k4];
      const int f = hhf * 32 + k4 * 4;
      sm.a.kt[(f + 0) * 128 + j] = val.x;
      sm.a.kt[(f + 1) * 128 + j] = val.y;
      sm.a.kt[(f + 2) * 128 + j] = val.z;
      sm.a.kt[(f + 3) * 128 + j] = val.w;
      ss += val.x * val.x + val.y * val.y + val.z * val.z + val.w * val.w;
    }
    atomicAdd(&sm.a.nrm[j], ss);
  }
  __syncthreads();
  if (tid < 128) {
    const float n = sqrtf(sm.a.nrm[tid]) + 1e-6f;
    sm.a.nrm[tid] = 0.125f / n;
  }
  float4 vreg[8];
  {
    const int j = tid >> 1, hhf = tid & 1;
    const float4* vsrc =
        (const float4*)(v + ((size_t)b * SS + sm.a.tk[j]) * DD) + hhf * 8;
#pragma unroll
    for (int k4 = 0; k4 < 8; k4++) vreg[k4] = vsrc[k4];
  }
  __syncthreads();

  const int qi0 = (tid & 15) * 4;
  const int j0g = (tid >> 4) * 8;
  const int kg = tid >> 4;
  float acc[4][8];
#pragma unroll
  for (int i = 0; i < 4; i++)
#pragma unroll
    for (int j = 0; j < 8; j++) acc[i][j] = 0.f;

#pragma unroll 8
  for (int f = 0; f < DD; f++) {
    float4 qv = *(const float4*)&sm.a.qt[f * 64 + qi0];
    float4 k0 = *(const float4*)&sm.a.kt[f * 128 + j0g];
    float4 k1 = *(const float4*)&sm.a.kt[f * 128 + j0g + 4];
    float qa[4] = {qv.x, qv.y, qv.z, qv.w};
    float ka[8] = {k0.x, k0.y, k0.z, k0.w, k1.x, k1.y, k1.z, k1.w};
#pragma unroll
    for (int i = 0; i < 4; i++)
#pragma unroll
      for (int j = 0; j < 8; j++) acc[i][j] = fmaf(qa[i], ka[j], acc[i][j]);
  }

  int tqr[4];
#pragma unroll
  for (int i = 0; i < 4; i++) tqr[i] = sm.a.tq[qi0 + i];
  int tkr[8]; float scl[8];
#pragma unroll
  for (int j = 0; j < 8; j++) {
    tkr[j] = sm.a.tk[j0g + j];
    scl[j] = sm.a.nrm[j0g + j];
  }
#pragma unroll
  for (int i = 0; i < 4; i++)
#pragma unroll
    for (int j = 0; j < 8; j++) {
      const float dv = acc[i][j] * scl[j];
      acc[i][j] = (tqr[i] == tkr[j]) ? -50000.0f : dv;
    }

  float pmax[4];
#pragma unroll
  for (int i = 0; i < 4; i++) {
    float m = acc[i][0];
#pragma unroll
    for (int j = 1; j < 8; j++) m = fmaxf(m, acc[i][j]);
    pmax[i] = m;
  }
#pragma unroll
  for (int i = 0; i < 4; i++) sm.a.red[kg * 64 + qi0 + i] = pmax[i];
  __syncthreads();
  if (tid < 64) {
    float m = -3.0e38f;
#pragma unroll
    for (int g = 0; g < 16; g++) m = fmaxf(m, sm.a.red[g * 64 + tid]);
    sm.a.rmax[tid] = m;
  }
  __syncthreads();
  float psum[4];
#pragma unroll
  for (int i = 0; i < 4; i++) {
    const float rm = sm.a.rmax[qi0 + i];
    float s = 0.f;
#pragma unroll
    for (int j = 0; j < 8; j++) {
      const float e = __expf(acc[i][j] - rm);
      acc[i][j] = e;
      s += e;
    }
    psum[i] = s;
  }
#pragma unroll
  for (int i = 0; i < 4; i++) sm.a.red[kg * 64 + qi0 + i] = psum[i];
  __syncthreads();
  if (tid < 64) {
    float s = 0.f;
#pragma unroll
    for (int g = 0; g < 16; g++) s += sm.a.red[g * 64 + tid];
    sm.a.rsum[tid] = s;
  }
  __syncthreads();
  float lse[4], isum[4];
#pragma unroll
  for (int i = 0; i < 4; i++) {
    const float rm = sm.a.rmax[qi0 + i];
    const float s = sm.a.rsum[qi0 + i];
    isum[i] = 1.0f / s;
    lse[i] = __logf(s) + rm;
  }
  __syncthreads();

#pragma unroll
  for (int j = 0; j < 8; j++)
#pragma unroll
    for (int i = 0; i < 4; i++)
      sm.p.pt[(j0g + j) * 64 + qi0 + i] = acc[i][j] * isum[i];
  {
    const int j = tid >> 1, hhf = tid & 1;
#pragma unroll
    for (int k4 = 0; k4 < 8; k4++)
      *(float4*)&sm.p.vs[j * 64 + hhf * 32 + k4 * 4] = vreg[k4];
  }
  __syncthreads();

  const int f0 = (tid >> 4) * 4;
  float o[4][4];
#pragma unroll
  for (int i = 0; i < 4; i++)
#pragma unroll
    for (int j = 0; j < 4; j++) o[i][j] = 0.f;

#pragma unroll 8
  for (int j = 0; j < 128; j++) {
    float4 pv = *(const float4*)&sm.p.pt[j * 64 + qi0];
    float4 vv = *(const float4*)&sm.p.vs[j * 64 + f0];
    float pa[4] = {pv.x, pv.y, pv.z, pv.w};
    float va[4] = {vv.x, vv.y, vv.z, vv.w};
#pragma unroll
    for (int i = 0; i < 4; i++)
#pragma unroll
      for (int j2 = 0; j2 < 4; j2++) o[i][j2] = fmaf(pa[i], va[j2], o[i][j2]);
  }

#pragma unroll
  for (int i = 0; i < 4; i++) {
    const float w = __expf(lse[i]);
    float* dst = num + ((size_t)b * SS + tqr[i]) * DD + f0;
#pragma unroll
    for (int j = 0; j < 4; j++) atomicAdd(dst + j, o[i][j] * w);
    if (kg == 0) atomicAdd(den + (size_t)b * SS + tqr[i], w);
  }
}

__global__ __launch_bounds__(256) void k_final(float* __restrict__ o,
                                               const float* __restrict__ den) {
  const size_t i = (size_t)blockIdx.x * 256 + threadIdx.x;
  o[i] = o[i] / den[i >> 6];
}

extern "C" void kernel_launch(void* const* d_in, const int* in_sizes, int n_in,
                              void* d_out, int out_size, void* d_ws,
                              size_t ws_size, hipStream_t stream) {
  const float* qk  = (const float*)d_in[0];
  const float* v   = (const float*)d_in[1];
  const float* rot = (const float*)d_in[2];

  float* out_attn = (float*)d_out;                      // B*S*D floats
  float* buckets_out = out_attn + (size_t)BB * SS * DD; // B*H*S floats

  const size_t BHS = (size_t)BB * HH * SS;
  int* bucket_local = (int*)d_ws;                 // BHS ints
  int* sort_t = bucket_local + BHS;               // BHS ints
  const size_t NEED = BHS * 4 * 4 + BHS * DD * 4; // bl+st+ipos+lse + so

  if (ws_size >= NEED) {
    int* ipos = sort_t + BHS;
    float* lse = (float*)(ipos + BHS);
    float* so = lse + BHS;

    k_hash<<<dim3(BB * HH, SS / 256), 256, 0, stream>>>(qk, rot, bucket_local,
                                                        buckets_out);
    k_sort<<<BB * HH, 256, 0, stream>>>(bucket_local, sort_t, ipos);
    k_attn_mfma<<<BB * NCH, 256, 0, stream>>>(qk, v, sort_t, so, lse);
    k_combine<<<(BB * SS * DD) / 256, 256, 0, stream>>>(so, lse, ipos, out_attn);
  } else {
    float* den = (float*)(sort_t + 2 * BHS);      // reuse ipos slot
    int* ipos = sort_t + BHS;                     // still written by k_sort
    hipMemsetAsync(out_attn, 0, (size_t)BB * SS * DD * sizeof(float), stream);
    hipMemsetAsync(den, 0, (size_t)BB * SS * sizeof(float), stream);
    k_hash<<<dim3(BB * HH, SS / 256), 256, 0, stream>>>(qk, rot, bucket_local,
                                                        buckets_out);
    k_sort<<<BB * HH, 256, 0, stream>>>(bucket_local, sort_t, ipos);
    k_attn_atomic<<<BB * NCH, 256, 0, stream>>>(qk, v, sort_t, out_attn, den);
    k_final<<<(BB * SS * DD) / 256, 256, 0, stream>>>(out_attn, den);
  }
}